// Round 2
// baseline (15220.494 us; speedup 1.0000x reference)
//
#include <hip/hip_runtime.h>
#include <hip/hip_bf16.h>
#include <hip/hip_fp16.h>
#include <stdint.h>

#define T_STEPS 256
#define BATCH 512

typedef _Float16 h2_t __attribute__((ext_vector_type(2)));

__device__ __forceinline__ float fdot2(uint32_t w, uint32_t c, float acc) {
#if __has_builtin(__builtin_amdgcn_fdot2)
    h2_t a, b;
    __builtin_memcpy(&a, &w, 4);
    __builtin_memcpy(&b, &c, 4);
    return __builtin_amdgcn_fdot2(a, b, acc, false);
#else
    union { uint32_t u; _Float16 h[2]; } A, B;
    A.u = w; B.u = c;
    return acc + (float)A.h[0]*(float)B.h[0] + (float)A.h[1]*(float)B.h[1];
#endif
}

__device__ __forceinline__ float sigmoidf_(float x) {
    return 1.f / (1.f + __expf(-x));
}
__device__ __forceinline__ float tanhf_(float x) {
    float ax = fabsf(x);
    float e = __expf(-2.f * ax);
    float r = (1.f - e) / (1.f + e);
    return copysignf(r, x);
}

// ---------------- prep: concat QCNN weights into one buffer ----------------
__global__ void concat_qw(const float* __restrict__ fm_w, const float* __restrict__ fm_b,
                          const float* __restrict__ c1_w, const float* __restrict__ c1_b,
                          const float* __restrict__ p1_w, const float* __restrict__ p1_b,
                          const float* __restrict__ c2_w, const float* __restrict__ c2_b,
                          const float* __restrict__ p2_w, const float* __restrict__ p2_b,
                          const float* __restrict__ c3_w, const float* __restrict__ c3_b,
                          float* __restrict__ qw) {
    for (int k = threadIdx.x; k < 780; k += 256) {
        float v;
        if      (k < 128) v = fm_w[k];
        else if (k < 144) v = fm_b[k-128];
        else if (k < 400) v = c1_w[k-144];
        else if (k < 416) v = c1_b[k-400];
        else if (k < 608) v = p1_w[k-416];
        else if (k < 620) v = p1_b[k-608];
        else if (k < 716) v = c2_w[k-620];
        else if (k < 724) v = c2_b[k-716];
        else if (k < 756) v = p2_w[k-724];
        else if (k < 760) v = p2_b[k-756];
        else if (k < 776) v = c3_w[k-760];
        else              v = c3_b[k-776];
        qw[k] = v;
    }
}

// ---------------- prep: pack LSTM gate weights to f16, K-reordered ----------------
// K layout per output o: k=0..255 -> h, k=256..259 -> x, k=260..263 -> zero pad.
// pair index p = 0..131 holds (2p, 2p+1). p<100 -> wregT[p][o]; p>=100 -> wtail[kq][o][c].
__global__ void pack_w(const float* __restrict__ f_w, const float* __restrict__ i_w,
                       const float* __restrict__ u_w, const float* __restrict__ o_w,
                       uint32_t* __restrict__ wregT, uint32_t* __restrict__ wtail) {
    int o = blockIdx.x;                       // 0..1023
    int p = blockIdx.y * 64 + threadIdx.x;    // 0..191
    if (p >= 132) return;
    int g = o >> 8, j = o & 255;
    const float* W = (g == 0) ? f_w : (g == 1) ? i_w : (g == 2) ? u_w : o_w;
    float v0 = 0.f, v1 = 0.f;
    int k0 = 2*p, k1 = 2*p + 1;
    if (k0 < 256) v0 = W[j*260 + 4 + k0]; else if (k0 < 260) v0 = W[j*260 + (k0-256)];
    if (k1 < 256) v1 = W[j*260 + 4 + k1]; else if (k1 < 260) v1 = W[j*260 + (k1-256)];
    union { uint32_t u; _Float16 h[2]; } P;
    P.h[0] = (_Float16)v0; P.h[1] = (_Float16)v1;
    if (p < 100) {
        wregT[p*1024 + o] = P.u;
    } else {
        int q = p - 100;                      // 0..31
        wtail[(((q >> 2) * 1024) + o) * 4 + (q & 3)] = P.u;
    }
}

// ---------------- QCNN feature extractor: one thread per (t,b) row ----------------
__global__ void qcnn_kernel(const float* __restrict__ in, const float* __restrict__ qw,
                            _Float16* __restrict__ feats) {
    int r = blockIdx.x * 256 + threadIdx.x;   // 0..131071
    const float* x = in + (size_t)r * 8;
    float v0[8];
#pragma unroll
    for (int i = 0; i < 8; ++i) v0[i] = x[i];
    float v1[16];
#pragma unroll
    for (int o = 0; o < 16; ++o) {
        float s = qw[128 + o];
#pragma unroll
        for (int i = 0; i < 8; ++i) s += qw[o*8 + i] * v0[i];
        v1[o] = tanhf_(s);
    }
    float v2[16];
#pragma unroll
    for (int o = 0; o < 16; ++o) {
        float s = qw[400 + o];
#pragma unroll
        for (int i = 0; i < 16; ++i) s += qw[144 + o*16 + i] * v1[i];
        v2[o] = tanhf_(s);
    }
    float v3[12];
#pragma unroll
    for (int o = 0; o < 12; ++o) {
        float s = qw[608 + o];
#pragma unroll
        for (int i = 0; i < 16; ++i) s += qw[416 + o*16 + i] * v2[i];
        v3[o] = tanhf_(s);
    }
    float v4[8];
#pragma unroll
    for (int o = 0; o < 8; ++o) {
        float s = qw[716 + o];
#pragma unroll
        for (int i = 0; i < 12; ++i) s += qw[620 + o*12 + i] * v3[i];
        v4[o] = tanhf_(s);
    }
    float v5[4];
#pragma unroll
    for (int o = 0; o < 4; ++o) {
        float s = qw[756 + o];
#pragma unroll
        for (int i = 0; i < 8; ++i) s += qw[724 + o*8 + i] * v4[i];
        v5[o] = tanhf_(s);
    }
    union { uint32_t u[2]; _Float16 h[4]; } P;
#pragma unroll
    for (int o = 0; o < 4; ++o) {
        float s = qw[776 + o];
#pragma unroll
        for (int i = 0; i < 4; ++i) s += qw[760 + o*4 + i] * v5[i];
        P.h[o] = (_Float16)tanhf_(s);
    }
    *reinterpret_cast<uint2*>(feats + (size_t)r * 4) = make_uint2(P.u[0], P.u[1]);
}

// ---------------- persistent LSTM: 256 blocks x 512 threads, 2 samples/block ----------------
#define DOT4(acc, warr, base, c4)                 \
    acc = fdot2(warr[(base)+0], (c4).x, acc);     \
    acc = fdot2(warr[(base)+1], (c4).y, acc);     \
    acc = fdot2(warr[(base)+2], (c4).z, acc);     \
    acc = fdot2(warr[(base)+3], (c4).w, acc);

#define DOTT(acc, tw, c4)                         \
    acc = fdot2((tw).x, (c4).x, acc);             \
    acc = fdot2((tw).y, (c4).y, acc);             \
    acc = fdot2((tw).z, (c4).z, acc);             \
    acc = fdot2((tw).w, (c4).w, acc);

// waves_per_eu(2,2): LDS (137 KB) already limits us to 1 block/CU = 2 waves/SIMD.
// Telling the allocator max-occupancy==2 unlocks the 256-VGPR budget so the
// 200 stationary weight regs stay in VGPRs (round 1: VGPR_Count=128 -> weights
// demoted to AGPR/scratch, +3600 VALU cyc/step of accvgpr traffic).
__global__ __attribute__((amdgpu_flat_work_group_size(512, 512), amdgpu_waves_per_eu(2, 2)))
void lstm_kernel(const uint32_t* __restrict__ wregT, const uint4* __restrict__ wtailG,
                 const _Float16* __restrict__ feats,
                 const float* __restrict__ f_b, const float* __restrict__ i_b,
                 const float* __restrict__ u_b, const float* __restrict__ o_b,
                 const float* __restrict__ head_w, const float* __restrict__ head_bp,
                 float* __restrict__ out) {
    __shared__ uint4 tailL[8192];                        // 128 KB  (weights K=200..263)
    __shared__ __align__(16) uint32_t combU[2][132];     // [sample][pair] f16x2: h(0..255),x(256..259),pad
    __shared__ float xbuf[4][256];                       // cross-pair gate exchange
    __shared__ float hw[256];                            // head weights
    __shared__ float red[8];                             // head partial sums

    const int tid = threadIdx.x;
    const int o0 = tid, o1 = tid + 512;
    const int j  = tid & 255;
    const int g0 = tid >> 8;                 // 0 -> (f,u) owner + sample 0; 1 -> (i,o) owner + sample 1
    const int s0 = blockIdx.x * 2;

    // stationary register weights: K pairs 0..99 for two outputs
    uint32_t w0[100], w1[100];
#pragma unroll
    for (int p = 0; p < 100; ++p) w0[p] = wregT[p*1024 + o0];
#pragma unroll
    for (int p = 0; p < 100; ++p) w1[p] = wregT[p*1024 + o1];

    const float bias0 = (g0 == 0 ? f_b : i_b)[j];
    const float bias1 = (g0 == 0 ? u_b : o_b)[j];
    const float hb = head_bp[0];

    for (int idx = tid; idx < 8192; idx += 512) tailL[idx] = wtailG[idx];
    if (tid < 256) hw[tid] = head_w[tid];
    _Float16* combH = reinterpret_cast<_Float16*>(&combU[0][0]);
    for (int idx = tid; idx < 528; idx += 512) combH[idx] = (_Float16)0.f;
    __syncthreads();
    if (tid < 8) {   // x_0
        const int bb = tid >> 2, k = tid & 3;
        combH[bb*264 + 256 + k] = feats[((size_t)0*BATCH + (s0+bb))*4 + k];
    }
    __syncthreads();

    const uint4* cb0p = reinterpret_cast<const uint4*>(&combU[0][0]);
    const uint4* cb1p = reinterpret_cast<const uint4*>(&combU[1][0]);

    float creg = 0.f;
#pragma unroll 1
    for (int t = 0; t < T_STEPS; ++t) {
        // prefetch next x into registers (latency hides under dot phase)
        _Float16 xnext = (_Float16)0.f;
        const bool xload = (tid < 8) && (t + 1 < T_STEPS);
        if (xload) {
            const int bb = tid >> 2, k = tid & 3;
            xnext = feats[((size_t)(t+1)*BATCH + (s0+bb))*4 + k];
        }

        // a00 = gateA(sample0), a01 = gateA(sample1), a10 = gateB(s0), a11 = gateB(s1)
        // gateA = f (g0==0) / i (g0==1); gateB = u (g0==0) / o (g0==1)
        float a00 = bias0, a01 = bias0, a10 = bias1, a11 = bias1;
#pragma unroll
        for (int q = 0; q < 25; ++q) {
            const uint4 c0 = cb0p[q];
            const uint4 c1 = cb1p[q];
            DOT4(a00, w0, 4*q, c0)
            DOT4(a01, w0, 4*q, c1)
            DOT4(a10, w1, 4*q, c0)
            DOT4(a11, w1, 4*q, c1)
        }
#pragma unroll
        for (int q = 0; q < 8; ++q) {
            const uint4 tw0 = tailL[q*1024 + o0];
            const uint4 tw1 = tailL[q*1024 + o1];
            const uint4 c0 = cb0p[25 + q];
            const uint4 c1 = cb1p[25 + q];
            DOTT(a00, tw0, c0)
            DOTT(a01, tw0, c1)
            DOTT(a10, tw1, c0)
            DOTT(a11, tw1, c1)
        }
        // pair exchange: thread j keeps sample-0 work, thread j+256 keeps sample-1;
        // each passes the partner the two pre-activations it needs (2 wr + 2 rd vs 4+4).
        if (g0 == 0) { xbuf[0][j] = a01; xbuf[1][j] = a11; }   // f(s1), u(s1)
        else         { xbuf[2][j] = a00; xbuf[3][j] = a10; }   // i(s0), o(s0)
        __syncthreads();                                  // (A)

        float fpre, ipre, upre, opre;
        if (g0 == 0) { fpre = a00;       upre = a10;       ipre = xbuf[2][j]; opre = xbuf[3][j]; }
        else         { fpre = xbuf[0][j]; upre = xbuf[1][j]; ipre = a01;       opre = a11; }

        const float fg = sigmoidf_(fpre);
        const float ig = sigmoidf_(ipre);
        const float ug = tanhf_(upre);
        const float og = sigmoidf_(opre);
        creg = fg * creg + ig * ug;
        const float h = og * tanhf_(creg);

        float p = h * hw[j];
#pragma unroll
        for (int off = 32; off > 0; off >>= 1) p += __shfl_down(p, off);
        if ((tid & 63) == 0) red[tid >> 6] = p;

        combH[g0*264 + j] = (_Float16)h;
        if (xload) {
            const int bb = tid >> 2, k = tid & 3;
            combH[bb*264 + 256 + k] = xnext;
        }
        __syncthreads();                                  // (B)

        if (tid < 2) {
            out[(size_t)t*BATCH + s0 + tid] =
                red[tid*4+0] + red[tid*4+1] + red[tid*4+2] + red[tid*4+3] + hb;
        }
    }
}

extern "C" void kernel_launch(void* const* d_in, const int* in_sizes, int n_in,
                              void* d_out, int out_size, void* d_ws, size_t ws_size,
                              hipStream_t stream) {
    const float* inputs = (const float*)d_in[0];
    const float* fm_w = (const float*)d_in[1];  const float* fm_b = (const float*)d_in[2];
    const float* c1_w = (const float*)d_in[3];  const float* c1_b = (const float*)d_in[4];
    const float* p1_w = (const float*)d_in[5];  const float* p1_b = (const float*)d_in[6];
    const float* c2_w = (const float*)d_in[7];  const float* c2_b = (const float*)d_in[8];
    const float* p2_w = (const float*)d_in[9];  const float* p2_b = (const float*)d_in[10];
    const float* c3_w = (const float*)d_in[11]; const float* c3_b = (const float*)d_in[12];
    const float* f_w  = (const float*)d_in[13]; const float* f_b  = (const float*)d_in[14];
    const float* i_w  = (const float*)d_in[15]; const float* i_b  = (const float*)d_in[16];
    const float* u_w  = (const float*)d_in[17]; const float* u_b  = (const float*)d_in[18];
    const float* o_w  = (const float*)d_in[19]; const float* o_b  = (const float*)d_in[20];
    const float* head_w = (const float*)d_in[21];
    const float* head_b = (const float*)d_in[22];

    // workspace layout (all 16B aligned)
    uint32_t*  wregT = (uint32_t*)d_ws;                               // 409600 B
    uint32_t*  wtail = (uint32_t*)((char*)d_ws + 409600);             // 131072 B
    _Float16*  feats = (_Float16*)((char*)d_ws + 540672);             // 1048576 B
    float*     qw    = (float*)((char*)d_ws + 1589248);               // 3120 B

    hipLaunchKernelGGL(concat_qw, dim3(1), dim3(256), 0, stream,
                       fm_w, fm_b, c1_w, c1_b, p1_w, p1_b, c2_w, c2_b,
                       p2_w, p2_b, c3_w, c3_b, qw);
    hipLaunchKernelGGL(pack_w, dim3(1024, 3), dim3(64), 0, stream,
                       f_w, i_w, u_w, o_w, wregT, wtail);
    hipLaunchKernelGGL(qcnn_kernel, dim3(512), dim3(256), 0, stream,
                       inputs, qw, feats);
    hipLaunchKernelGGL(lstm_kernel, dim3(256), dim3(512), 0, stream,
                       wregT, (const uint4*)wtail, feats,
                       f_b, i_b, u_b, o_b, head_w, head_b, (float*)d_out);
}

// Round 3
// 870.057 us; speedup vs baseline: 17.4937x; 17.4937x over previous
//
#include <hip/hip_runtime.h>
#include <hip/hip_bf16.h>
#include <hip/hip_fp16.h>
#include <stdint.h>

#define T_STEPS 256
#define BATCH 512

typedef _Float16 h2_t __attribute__((ext_vector_type(2)));

__device__ __forceinline__ float fdot2(uint32_t w, uint32_t c, float acc) {
#if __has_builtin(__builtin_amdgcn_fdot2)
    h2_t a, b;
    __builtin_memcpy(&a, &w, 4);
    __builtin_memcpy(&b, &c, 4);
    return __builtin_amdgcn_fdot2(a, b, acc, false);
#else
    union { uint32_t u; _Float16 h[2]; } A, B;
    A.u = w; B.u = c;
    return acc + (float)A.h[0]*(float)B.h[0] + (float)A.h[1]*(float)B.h[1];
#endif
}

__device__ __forceinline__ float sigmoidf_(float x) {
    return 1.f / (1.f + __expf(-x));
}
__device__ __forceinline__ float tanhf_(float x) {
    float ax = fabsf(x);
    float e = __expf(-2.f * ax);
    float r = (1.f - e) / (1.f + e);
    return copysignf(r, x);
}

// ---------------- prep: concat QCNN weights into one buffer ----------------
__global__ void concat_qw(const float* __restrict__ fm_w, const float* __restrict__ fm_b,
                          const float* __restrict__ c1_w, const float* __restrict__ c1_b,
                          const float* __restrict__ p1_w, const float* __restrict__ p1_b,
                          const float* __restrict__ c2_w, const float* __restrict__ c2_b,
                          const float* __restrict__ p2_w, const float* __restrict__ p2_b,
                          const float* __restrict__ c3_w, const float* __restrict__ c3_b,
                          float* __restrict__ qw) {
    for (int k = threadIdx.x; k < 780; k += 256) {
        float v;
        if      (k < 128) v = fm_w[k];
        else if (k < 144) v = fm_b[k-128];
        else if (k < 400) v = c1_w[k-144];
        else if (k < 416) v = c1_b[k-400];
        else if (k < 608) v = p1_w[k-416];
        else if (k < 620) v = p1_b[k-608];
        else if (k < 716) v = c2_w[k-620];
        else if (k < 724) v = c2_b[k-716];
        else if (k < 756) v = p2_w[k-724];
        else if (k < 760) v = p2_b[k-756];
        else if (k < 776) v = c3_w[k-760];
        else              v = c3_b[k-776];
        qw[k] = v;
    }
}

// ---------------- prep: pack LSTM gate weights to f16, K-reordered ----------------
// K layout per output o: k=0..255 -> h, k=256..259 -> x, k=260..263 -> zero pad.
// pair index p = 0..131 holds (2p, 2p+1). p<100 -> wregT[p][o]; p>=100 -> wtail[kq][o][c].
__global__ void pack_w(const float* __restrict__ f_w, const float* __restrict__ i_w,
                       const float* __restrict__ u_w, const float* __restrict__ o_w,
                       uint32_t* __restrict__ wregT, uint32_t* __restrict__ wtail) {
    int o = blockIdx.x;                       // 0..1023
    int p = blockIdx.y * 64 + threadIdx.x;    // 0..191
    if (p >= 132) return;
    int g = o >> 8, j = o & 255;
    const float* W = (g == 0) ? f_w : (g == 1) ? i_w : (g == 2) ? u_w : o_w;
    float v0 = 0.f, v1 = 0.f;
    int k0 = 2*p, k1 = 2*p + 1;
    if (k0 < 256) v0 = W[j*260 + 4 + k0]; else if (k0 < 260) v0 = W[j*260 + (k0-256)];
    if (k1 < 256) v1 = W[j*260 + 4 + k1]; else if (k1 < 260) v1 = W[j*260 + (k1-256)];
    union { uint32_t u; _Float16 h[2]; } P;
    P.h[0] = (_Float16)v0; P.h[1] = (_Float16)v1;
    if (p < 100) {
        wregT[p*1024 + o] = P.u;
    } else {
        int q = p - 100;                      // 0..31
        wtail[(((q >> 2) * 1024) + o) * 4 + (q & 3)] = P.u;
    }
}

// ---------------- QCNN feature extractor: one thread per (t,b) row ----------------
__global__ void qcnn_kernel(const float* __restrict__ in, const float* __restrict__ qw,
                            _Float16* __restrict__ feats) {
    int r = blockIdx.x * 256 + threadIdx.x;   // 0..131071
    const float* x = in + (size_t)r * 8;
    float v0[8];
#pragma unroll
    for (int i = 0; i < 8; ++i) v0[i] = x[i];
    float v1[16];
#pragma unroll
    for (int o = 0; o < 16; ++o) {
        float s = qw[128 + o];
#pragma unroll
        for (int i = 0; i < 8; ++i) s += qw[o*8 + i] * v0[i];
        v1[o] = tanhf_(s);
    }
    float v2[16];
#pragma unroll
    for (int o = 0; o < 16; ++o) {
        float s = qw[400 + o];
#pragma unroll
        for (int i = 0; i < 16; ++i) s += qw[144 + o*16 + i] * v1[i];
        v2[o] = tanhf_(s);
    }
    float v3[12];
#pragma unroll
    for (int o = 0; o < 12; ++o) {
        float s = qw[608 + o];
#pragma unroll
        for (int i = 0; i < 16; ++i) s += qw[416 + o*16 + i] * v2[i];
        v3[o] = tanhf_(s);
    }
    float v4[8];
#pragma unroll
    for (int o = 0; o < 8; ++o) {
        float s = qw[716 + o];
#pragma unroll
        for (int i = 0; i < 12; ++i) s += qw[620 + o*12 + i] * v3[i];
        v4[o] = tanhf_(s);
    }
    float v5[4];
#pragma unroll
    for (int o = 0; o < 4; ++o) {
        float s = qw[756 + o];
#pragma unroll
        for (int i = 0; i < 8; ++i) s += qw[724 + o*8 + i] * v4[i];
        v5[o] = tanhf_(s);
    }
    union { uint32_t u[2]; _Float16 h[4]; } P;
#pragma unroll
    for (int o = 0; o < 4; ++o) {
        float s = qw[776 + o];
#pragma unroll
        for (int i = 0; i < 4; ++i) s += qw[760 + o*4 + i] * v5[i];
        P.h[o] = (_Float16)tanhf_(s);
    }
    *reinterpret_cast<uint2*>(feats + (size_t)r * 4) = make_uint2(P.u[0], P.u[1]);
}

// ---------------- persistent LSTM: 256 blocks x 512 threads, 2 samples/block ----------------
#define DOT4(acc, warr, base, c4)                 \
    acc = fdot2(warr[(base)+0], (c4).x, acc);     \
    acc = fdot2(warr[(base)+1], (c4).y, acc);     \
    acc = fdot2(warr[(base)+2], (c4).z, acc);     \
    acc = fdot2(warr[(base)+3], (c4).w, acc);

#define DOTT(acc, tw, c4)                         \
    acc = fdot2((tw).x, (c4).x, acc);             \
    acc = fdot2((tw).y, (c4).y, acc);             \
    acc = fdot2((tw).z, (c4).z, acc);             \
    acc = fdot2((tw).w, (c4).w, acc);

// __launch_bounds__(512,2) is the known-good allocator operating point:
// 128 arch VGPR + AGPR-resident weights, ZERO scratch spills (round 1).
// waves_per_eu(2,2) (round 2) demoted the weight arrays to scratch: 17.9 GB
// of FETCH per dispatch, 15x regression. Do not touch.
//
// Gate mapping: wave w (0..7), lane ln (0..63). gsel = ln>>5, jj = w*32+(ln&31).
// Thread owns gate rows o0 = gsel*256+jj (f or i) and o1 = o0+512 (u or o) for
// BOTH samples. The 4 gates of output jj live on lanes ln and ln^32 of the same
// wave -> exchange via 2x shfl_xor, no LDS, no barrier. One barrier per step;
// comb and red double-buffered by t&1 to make that race-free.
__global__ __launch_bounds__(512, 2)
void lstm_kernel(const uint32_t* __restrict__ wregT, const uint4* __restrict__ wtailG,
                 const _Float16* __restrict__ feats,
                 const float* __restrict__ f_b, const float* __restrict__ i_b,
                 const float* __restrict__ u_b, const float* __restrict__ o_b,
                 const float* __restrict__ head_w, const float* __restrict__ head_bp,
                 float* __restrict__ out) {
    __shared__ uint4 tailL[8192];                        // 128 KB  (weights K=200..263)
    __shared__ __align__(16) uint32_t combU[2][2][132];  // [buf][sample][pair] f16x2
    __shared__ float hw[256];                            // head weights
    __shared__ float red[2][2][8];                       // [buf][sample][wave] head partials

    const int tid  = threadIdx.x;
    const int w    = tid >> 6;
    const int ln   = tid & 63;
    const int gsel = ln >> 5;                 // 0 -> (f,u) rows; 1 -> (i,o) rows
    const int jj   = w * 32 + (ln & 31);      // output row 0..255
    const int vt   = gsel * 256 + jj;
    const int o0   = vt, o1 = vt + 512;
    const int s0   = blockIdx.x * 2;

    // stationary register weights: K pairs 0..99 for two gate rows
    uint32_t w0[100], w1[100];
#pragma unroll
    for (int p = 0; p < 100; ++p) w0[p] = wregT[p*1024 + o0];
#pragma unroll
    for (int p = 0; p < 100; ++p) w1[p] = wregT[p*1024 + o1];

    const float bias0 = (gsel == 0 ? f_b : i_b)[jj];
    const float bias1 = (gsel == 0 ? u_b : o_b)[jj];
    const float hb = head_bp[0];

    for (int idx = tid; idx < 8192; idx += 512) tailL[idx] = wtailG[idx];
    if (tid < 256) hw[tid] = head_w[tid];
    for (int idx = tid; idx < 2*2*132; idx += 512) (&combU[0][0][0])[idx] = 0u;
    __syncthreads();
    if (tid < 8) {   // x_0 into buffer 0
        const int bb = tid >> 2, k = tid & 3;
        reinterpret_cast<_Float16*>(&combU[0][0][0])[bb*264 + 256 + k] =
            feats[((size_t)0*BATCH + (s0+bb))*4 + k];
    }
    __syncthreads();

    float creg = 0.f;   // c-state for (jj, sample = gsel)
#pragma unroll 1
    for (int t = 0; t < T_STEPS; ++t) {
        // prefetch next x into registers (latency hides under dot phase)
        _Float16 xnext = (_Float16)0.f;
        const bool xload = (tid < 8) && (t + 1 < T_STEPS);
        if (xload) {
            const int bb = tid >> 2, k = tid & 3;
            xnext = feats[((size_t)(t+1)*BATCH + (s0+bb))*4 + k];
        }

        const uint4* cb0 = reinterpret_cast<const uint4*>(&combU[t & 1][0][0]);
        const uint4* cb1 = reinterpret_cast<const uint4*>(&combU[t & 1][1][0]);

        // tail pipeline: preload 2 chunks; their latency hides under the reg-dot phase
        uint4 ta[8], tb[8];
        ta[0] = tailL[o0];        tb[0] = tailL[o1];
        ta[1] = tailL[1024 + o0]; tb[1] = tailL[1024 + o1];

        // a00 = gateA(s0), a01 = gateA(s1), a10 = gateB(s0), a11 = gateB(s1)
        float a00 = bias0, a01 = bias0, a10 = bias1, a11 = bias1;
#pragma unroll
        for (int q = 0; q < 25; ++q) {
            const uint4 c0 = cb0[q];
            const uint4 c1 = cb1[q];
            DOT4(a00, w0, 4*q, c0)
            DOT4(a01, w0, 4*q, c1)
            DOT4(a10, w1, 4*q, c0)
            DOT4(a11, w1, 4*q, c1)
        }
#pragma unroll
        for (int q = 0; q < 8; ++q) {
            if (q < 6) {   // rolling 2-ahead prefetch
                ta[q+2] = tailL[(q+2)*1024 + o0];
                tb[q+2] = tailL[(q+2)*1024 + o1];
            }
            const uint4 c0 = cb0[25 + q];
            const uint4 c1 = cb1[25 + q];
            DOTT(a00, ta[q], c0)
            DOTT(a01, ta[q], c1)
            DOTT(a10, tb[q], c0)
            DOTT(a11, tb[q], c1)
        }

        // gate exchange within the lane pair (ln, ln^32): 2 shuffles, no LDS
        const float X  = gsel ? a00 : a01;     // send f_s1 / recv i_s0  (gsel 0)
        const float Y  = gsel ? a10 : a11;     // send u_s1 / recv o_s0  (gsel 0)
        const float rX = __shfl_xor(X, 32);
        const float rY = __shfl_xor(Y, 32);
        const float fpre = gsel ? rX  : a00;
        const float ipre = gsel ? a01 : rX;
        const float upre = gsel ? rY  : a10;
        const float opre = gsel ? a11 : rY;

        const float fg = sigmoidf_(fpre);
        const float ig = sigmoidf_(ipre);
        const float ug = tanhf_(upre);
        const float og = sigmoidf_(opre);
        creg = fg * creg + ig * ug;
        const float h = og * tanhf_(creg);

        // head partial: reduce each 32-lane half (one sample) of the wave
        float p = h * hw[jj];
        p += __shfl_down(p, 16);
        p += __shfl_down(p, 8);
        p += __shfl_down(p, 4);
        p += __shfl_down(p, 2);
        p += __shfl_down(p, 1);
        if ((ln & 31) == 0) red[t & 1][gsel][w] = p;

        // write h (and prefetched x) into the NEXT buffer
        _Float16* nb = reinterpret_cast<_Float16*>(&combU[(t + 1) & 1][0][0]);
        nb[gsel*264 + jj] = (_Float16)h;
        if (xload) {
            const int bb = tid >> 2, k = tid & 3;
            nb[bb*264 + 256 + k] = xnext;
        }
        __syncthreads();                                  // single barrier per step

        if (tid < 2) {
            const float* r = red[t & 1][tid];
            out[(size_t)t*BATCH + s0 + tid] =
                ((r[0]+r[1]) + (r[2]+r[3])) + ((r[4]+r[5]) + (r[6]+r[7])) + hb;
        }
    }
}

extern "C" void kernel_launch(void* const* d_in, const int* in_sizes, int n_in,
                              void* d_out, int out_size, void* d_ws, size_t ws_size,
                              hipStream_t stream) {
    const float* inputs = (const float*)d_in[0];
    const float* fm_w = (const float*)d_in[1];  const float* fm_b = (const float*)d_in[2];
    const float* c1_w = (const float*)d_in[3];  const float* c1_b = (const float*)d_in[4];
    const float* p1_w = (const float*)d_in[5];  const float* p1_b = (const float*)d_in[6];
    const float* c2_w = (const float*)d_in[7];  const float* c2_b = (const float*)d_in[8];
    const float* p2_w = (const float*)d_in[9];  const float* p2_b = (const float*)d_in[10];
    const float* c3_w = (const float*)d_in[11]; const float* c3_b = (const float*)d_in[12];
    const float* f_w  = (const float*)d_in[13]; const float* f_b  = (const float*)d_in[14];
    const float* i_w  = (const float*)d_in[15]; const float* i_b  = (const float*)d_in[16];
    const float* u_w  = (const float*)d_in[17]; const float* u_b  = (const float*)d_in[18];
    const float* o_w  = (const float*)d_in[19]; const float* o_b  = (const float*)d_in[20];
    const float* head_w = (const float*)d_in[21];
    const float* head_b = (const float*)d_in[22];

    // workspace layout (all 16B aligned)
    uint32_t*  wregT = (uint32_t*)d_ws;                               // 409600 B
    uint32_t*  wtail = (uint32_t*)((char*)d_ws + 409600);             // 131072 B
    _Float16*  feats = (_Float16*)((char*)d_ws + 540672);             // 1048576 B
    float*     qw    = (float*)((char*)d_ws + 1589248);               // 3120 B

    hipLaunchKernelGGL(concat_qw, dim3(1), dim3(256), 0, stream,
                       fm_w, fm_b, c1_w, c1_b, p1_w, p1_b, c2_w, c2_b,
                       p2_w, p2_b, c3_w, c3_b, qw);
    hipLaunchKernelGGL(pack_w, dim3(1024, 3), dim3(64), 0, stream,
                       f_w, i_w, u_w, o_w, wregT, wtail);
    hipLaunchKernelGGL(qcnn_kernel, dim3(512), dim3(256), 0, stream,
                       inputs, qw, feats);
    hipLaunchKernelGGL(lstm_kernel, dim3(256), dim3(512), 0, stream,
                       wregT, (const uint4*)wtail, feats,
                       f_b, i_b, u_b, o_b, head_w, head_b, (float*)d_out);
}

// Round 4
// 859.108 us; speedup vs baseline: 17.7166x; 1.0127x over previous
//
#include <hip/hip_runtime.h>
#include <hip/hip_bf16.h>
#include <hip/hip_fp16.h>
#include <stdint.h>

#define T_STEPS 256
#define BATCH 512

typedef _Float16 f16x8 __attribute__((ext_vector_type(8)));
typedef float    f32x4 __attribute__((ext_vector_type(4)));

__device__ __forceinline__ float sigmoidf_(float x) {
    return 1.f / (1.f + __expf(-x));
}
__device__ __forceinline__ float tanhf_(float x) {
    float ax = fabsf(x);
    float e = __expf(-2.f * ax);
    float r = (1.f - e) / (1.f + e);
    return copysignf(r, x);
}

// ---------------- prep: concat QCNN weights into one buffer ----------------
__global__ void concat_qw(const float* __restrict__ fm_w, const float* __restrict__ fm_b,
                          const float* __restrict__ c1_w, const float* __restrict__ c1_b,
                          const float* __restrict__ p1_w, const float* __restrict__ p1_b,
                          const float* __restrict__ c2_w, const float* __restrict__ c2_b,
                          const float* __restrict__ p2_w, const float* __restrict__ p2_b,
                          const float* __restrict__ c3_w, const float* __restrict__ c3_b,
                          float* __restrict__ qw) {
    for (int k = threadIdx.x; k < 780; k += 256) {
        float v;
        if      (k < 128) v = fm_w[k];
        else if (k < 144) v = fm_b[k-128];
        else if (k < 400) v = c1_w[k-144];
        else if (k < 416) v = c1_b[k-400];
        else if (k < 608) v = p1_w[k-416];
        else if (k < 620) v = p1_b[k-608];
        else if (k < 716) v = c2_w[k-620];
        else if (k < 724) v = c2_b[k-716];
        else if (k < 756) v = p2_w[k-724];
        else if (k < 760) v = p2_b[k-756];
        else if (k < 776) v = c3_w[k-760];
        else              v = c3_b[k-776];
        qw[k] = v;
    }
}

// ---------------- prep: pack LSTM h-weights as MFMA B-fragments (f16) ----------------
// v_mfma_f32_16x16x32_f16 B-fragment assumption: lane l holds col = l&15,
// k = (l>>4)*8 + e, e = 0..7 (4 VGPRs of f16x2). Any permutation of the
// k-element order cancels between A and B since we pack B and read A with the
// same mapping. bfragsG flat index: ((n*8 + q)*64 + l), n = N-tile (16 cols),
// q = K-tile (32 k), k_global = q*32 + (l>>4)*8 + e maps to W[j][4 + k_global]
// (reference in-dim order: x(0..3), h(4..259)).
__global__ void pack_bfrag(const float* __restrict__ f_w, const float* __restrict__ i_w,
                           const float* __restrict__ u_w, const float* __restrict__ o_w,
                           uint4* __restrict__ bfragsG) {
    int idx = blockIdx.x * 256 + threadIdx.x;      // 0..32767
    int l = idx & 63, q = (idx >> 6) & 7, n = idx >> 9;
    int col = n * 16 + (l & 15);
    int g = col >> 8, j = col & 255;
    const float* W = (g == 0) ? f_w : (g == 1) ? i_w : (g == 2) ? u_w : o_w;
    union { uint4 u; _Float16 h[8]; } P;
#pragma unroll
    for (int e = 0; e < 8; ++e) {
        int k = q * 32 + ((l >> 4) * 8) + e;       // 0..255 (h part only)
        P.h[e] = (_Float16)W[j * 260 + 4 + k];
    }
    bfragsG[idx] = P.u;
}

// ---------------- prep: pack x-part weights xwG[g][k][j] f16 ----------------
__global__ void pack_xw(const float* __restrict__ f_w, const float* __restrict__ i_w,
                        const float* __restrict__ u_w, const float* __restrict__ o_w,
                        _Float16* __restrict__ xwG) {
    int t = blockIdx.x * 256 + threadIdx.x;        // 0..4095
    int g = t >> 10, k = (t >> 8) & 3, j = t & 255;
    const float* W = (g == 0) ? f_w : (g == 1) ? i_w : (g == 2) ? u_w : o_w;
    xwG[t] = (_Float16)W[j * 260 + k];
}

// ---------------- QCNN feature extractor: one thread per (t,b) row ----------------
__global__ void qcnn_kernel(const float* __restrict__ in, const float* __restrict__ qw,
                            _Float16* __restrict__ feats) {
    int r = blockIdx.x * 256 + threadIdx.x;   // 0..131071
    const float* x = in + (size_t)r * 8;
    float v0[8];
#pragma unroll
    for (int i = 0; i < 8; ++i) v0[i] = x[i];
    float v1[16];
#pragma unroll
    for (int o = 0; o < 16; ++o) {
        float s = qw[128 + o];
#pragma unroll
        for (int i = 0; i < 8; ++i) s += qw[o*8 + i] * v0[i];
        v1[o] = tanhf_(s);
    }
    float v2[16];
#pragma unroll
    for (int o = 0; o < 16; ++o) {
        float s = qw[400 + o];
#pragma unroll
        for (int i = 0; i < 16; ++i) s += qw[144 + o*16 + i] * v1[i];
        v2[o] = tanhf_(s);
    }
    float v3[12];
#pragma unroll
    for (int o = 0; o < 12; ++o) {
        float s = qw[608 + o];
#pragma unroll
        for (int i = 0; i < 16; ++i) s += qw[416 + o*16 + i] * v2[i];
        v3[o] = tanhf_(s);
    }
    float v4[8];
#pragma unroll
    for (int o = 0; o < 8; ++o) {
        float s = qw[716 + o];
#pragma unroll
        for (int i = 0; i < 12; ++i) s += qw[620 + o*12 + i] * v3[i];
        v4[o] = tanhf_(s);
    }
    float v5[4];
#pragma unroll
    for (int o = 0; o < 4; ++o) {
        float s = qw[756 + o];
#pragma unroll
        for (int i = 0; i < 8; ++i) s += qw[724 + o*8 + i] * v4[i];
        v5[o] = tanhf_(s);
    }
    union { uint32_t u[2]; _Float16 h[4]; } P;
#pragma unroll
    for (int o = 0; o < 4; ++o) {
        float s = qw[776 + o];
#pragma unroll
        for (int i = 0; i < 4; ++i) s += qw[760 + o*4 + i] * v5[i];
        P.h[o] = (_Float16)tanhf_(s);
    }
    *reinterpret_cast<uint2*>(feats + (size_t)r * 4) = make_uint2(P.u[0], P.u[1]);
}

// ---------------- persistent MFMA LSTM: 256 blocks x 256 threads, 2 samples/block ----
// 4 waves, 1 wave/SIMD (launch_bounds(256,1) -> up to 512 unified VGPRs).
// Wave w owns N-tiles n = w*16 + m, m=0..15. K-tiles q=0..5 register-resident
// (96 frags = 384 VGPR), q=6..7 streamed from LDS (128 KB) each step.
// A: rows 0,1 = samples 0,1 (lane l reads combL[l&1]); rows 2-15 garbage (each
// C row depends only on its A row -> harmless). C layout (HW-verified m89):
// col = lane&15, row = (lane>>4)*4 + reg -> rows 0,1 are regs 0,1 of lanes 0-15.
__global__ __launch_bounds__(256, 1)
void lstm_kernel(const uint4* __restrict__ bfragsG, const _Float16* __restrict__ xwG,
                 const _Float16* __restrict__ feats,
                 const float* __restrict__ f_b, const float* __restrict__ i_b,
                 const float* __restrict__ u_b, const float* __restrict__ o_b,
                 const float* __restrict__ head_w, const float* __restrict__ head_bp,
                 float* __restrict__ out) {
    __shared__ uint4     bldsL[2][64][64];      // 131072 B : B-frags q=6,7
    __shared__ float     gatesL[1024][2];       //   8192 B : [col][sample] pre-acts
    __shared__ _Float16  combL[2][2][256];      //   2048 B : [buf][sample][k] h state
    __shared__ _Float16  xwL[4][4][256];        //   8192 B : x-part weights
    __shared__ float     biasL[4][256];         //   4096 B
    __shared__ float     hwL[256];              //   1024 B
    __shared__ float     xvL[2][2][4];          //     64 B : [buf][sample][k] x values
    __shared__ float     redL[2][4];            //     32 B : head partials

    const int tid = threadIdx.x;
    const int w   = tid >> 6;          // wave 0..3
    const int l   = tid & 63;          // lane
    const int s0  = blockIdx.x * 2;

    // ---- init LDS ----
    for (int i = tid; i < 8192; i += 256) {
        int n = i >> 7, qq = (i >> 6) & 1, ll = i & 63;
        bldsL[qq][n][ll] = bfragsG[(n * 8 + 6 + qq) * 64 + ll];
    }
    for (int i = tid; i < 512; i += 256)
        reinterpret_cast<uint4*>(&xwL[0][0][0])[i] = reinterpret_cast<const uint4*>(xwG)[i];
    biasL[0][tid] = f_b[tid]; biasL[1][tid] = i_b[tid];
    biasL[2][tid] = u_b[tid]; biasL[3][tid] = o_b[tid];
    hwL[tid] = head_w[tid];
    reinterpret_cast<uint32_t*>(&combL[0][0][0])[tid] = 0u;   // zero h_0 (buf 0)
    if (tid < 8) {
        int s = tid >> 2, k = tid & 3;
        xvL[0][s][k] = (float)feats[((size_t)0 * BATCH + (s0 + s)) * 4 + k];
    }

    // ---- register-resident B fragments: q = 0..5 ----
    f16x8 Breg[16][6];
#pragma unroll
    for (int m = 0; m < 16; ++m)
#pragma unroll
        for (int q = 0; q < 6; ++q)
            Breg[m][q] = *reinterpret_cast<const f16x8*>(
                bfragsG + ((w * 16 + m) * 8 + q) * 64 + l);

    const float hb = head_bp[0];
    __syncthreads();

    float c0 = 0.f, c1 = 0.f;          // c-state: thread tid owns output row j = tid
    const int j = tid;

#pragma unroll 1
    for (int t = 0; t < T_STEPS; ++t) {
        // phase 0: prefetch x_{t+1} (8 threads; hides under MFMA phase)
        if (tid < 8 && t + 1 < T_STEPS) {
            int s = tid >> 2, k = tid & 3;
            xvL[(t + 1) & 1][s][k] =
                (float)feats[((size_t)(t + 1) * BATCH + (s0 + s)) * 4 + k];
        }

        // phase 1: MFMA  C[2 x 1024] = comb[2 x 256] . W^T
        f32x4 C[16] = {};
        const _Float16* Abase = &combL[t & 1][l & 1][(l >> 4) * 8];
#pragma unroll
        for (int q = 0; q < 8; ++q) {
            f16x8 a = *reinterpret_cast<const f16x8*>(Abase + q * 32);
#pragma unroll
            for (int m = 0; m < 16; ++m) {
                f16x8 b;
                if (q < 6) b = Breg[m][q];
                else       b = *reinterpret_cast<const f16x8*>(&bldsL[q - 6][w * 16 + m][l]);
                C[m] = __builtin_amdgcn_mfma_f32_16x16x32_f16(a, b, C[m], 0, 0, 0);
            }
        }

        // phase 2: extract rows 0,1 (samples) -> gatesL
        if (l < 16) {
#pragma unroll
            for (int m = 0; m < 16; ++m) {
                float2 v = make_float2(C[m][0], C[m][1]);
                *reinterpret_cast<float2*>(&gatesL[w * 256 + m * 16 + l][0]) = v;
            }
        }
        __syncthreads();                               // (A)

        // phase 3: epilogue — thread j handles output row j for both samples
        float xs[2][4];
#pragma unroll
        for (int s = 0; s < 2; ++s)
#pragma unroll
            for (int k = 0; k < 4; ++k) xs[s][k] = xvL[t & 1][s][k];

        float pre[4][2];
#pragma unroll
        for (int g = 0; g < 4; ++g) {
            float2 gv = *reinterpret_cast<const float2*>(&gatesL[g * 256 + j][0]);
            float bias = biasL[g][j];
            float w0 = (float)xwL[g][0][j], w1 = (float)xwL[g][1][j];
            float w2 = (float)xwL[g][2][j], w3 = (float)xwL[g][3][j];
            pre[g][0] = gv.x + bias + xs[0][0]*w0 + xs[0][1]*w1 + xs[0][2]*w2 + xs[0][3]*w3;
            pre[g][1] = gv.y + bias + xs[1][0]*w0 + xs[1][1]*w1 + xs[1][2]*w2 + xs[1][3]*w3;
        }

        float p0 = 0.f, p1 = 0.f;
#pragma unroll
        for (int s = 0; s < 2; ++s) {
            float fg = sigmoidf_(pre[0][s]);
            float ig = sigmoidf_(pre[1][s]);
            float ug = tanhf_(pre[2][s]);
            float og = sigmoidf_(pre[3][s]);
            float cc = (s ? c1 : c0);
            cc = fg * cc + ig * ug;
            if (s) c1 = cc; else c0 = cc;
            float h = og * tanhf_(cc);
            combL[(t + 1) & 1][s][j] = (_Float16)h;
            float p = h * hwL[j];
            if (s) p1 = p; else p0 = p;
        }
#pragma unroll
        for (int off = 32; off; off >>= 1) {
            p0 += __shfl_down(p0, off);
            p1 += __shfl_down(p1, off);
        }
        if (l == 0) { redL[0][w] = p0; redL[1][w] = p1; }
        __syncthreads();                               // (B)

        if (tid < 2)
            out[(size_t)t * BATCH + s0 + tid] =
                ((redL[tid][0] + redL[tid][1]) + (redL[tid][2] + redL[tid][3])) + hb;
    }
}

extern "C" void kernel_launch(void* const* d_in, const int* in_sizes, int n_in,
                              void* d_out, int out_size, void* d_ws, size_t ws_size,
                              hipStream_t stream) {
    const float* inputs = (const float*)d_in[0];
    const float* fm_w = (const float*)d_in[1];  const float* fm_b = (const float*)d_in[2];
    const float* c1_w = (const float*)d_in[3];  const float* c1_b = (const float*)d_in[4];
    const float* p1_w = (const float*)d_in[5];  const float* p1_b = (const float*)d_in[6];
    const float* c2_w = (const float*)d_in[7];  const float* c2_b = (const float*)d_in[8];
    const float* p2_w = (const float*)d_in[9];  const float* p2_b = (const float*)d_in[10];
    const float* c3_w = (const float*)d_in[11]; const float* c3_b = (const float*)d_in[12];
    const float* f_w  = (const float*)d_in[13]; const float* f_b  = (const float*)d_in[14];
    const float* i_w  = (const float*)d_in[15]; const float* i_b  = (const float*)d_in[16];
    const float* u_w  = (const float*)d_in[17]; const float* u_b  = (const float*)d_in[18];
    const float* o_w  = (const float*)d_in[19]; const float* o_b  = (const float*)d_in[20];
    const float* head_w = (const float*)d_in[21];
    const float* head_b = (const float*)d_in[22];

    // workspace layout (16B aligned)
    uint4*     bfragsG = (uint4*)d_ws;                                // 524288 B
    _Float16*  xwG     = (_Float16*)((char*)d_ws + 524288);           //   8192 B
    _Float16*  feats   = (_Float16*)((char*)d_ws + 532480);           // 1048576 B
    float*     qw      = (float*)((char*)d_ws + 1581056);             //   3120 B

    hipLaunchKernelGGL(concat_qw, dim3(1), dim3(256), 0, stream,
                       fm_w, fm_b, c1_w, c1_b, p1_w, p1_b, c2_w, c2_b,
                       p2_w, p2_b, c3_w, c3_b, qw);
    hipLaunchKernelGGL(pack_bfrag, dim3(128), dim3(256), 0, stream,
                       f_w, i_w, u_w, o_w, bfragsG);
    hipLaunchKernelGGL(pack_xw, dim3(16), dim3(256), 0, stream,
                       f_w, i_w, u_w, o_w, xwG);
    hipLaunchKernelGGL(qcnn_kernel, dim3(512), dim3(256), 0, stream,
                       inputs, qw, feats);
    hipLaunchKernelGGL(lstm_kernel, dim3(256), dim3(256), 0, stream,
                       bfragsG, xwG, feats,
                       f_b, i_b, u_b, o_b, head_w, head_b, (float*)d_out);
}